// Round 1
// baseline (182.002 us; speedup 1.0000x reference)
//
#include <hip/hip_runtime.h>
#include <stdint.h>

#define N_Q   65536
#define N_S   65536
#define NB_H  26
#define PAD_H 28
#define KP    10
#define CIN   64
#define COUT  128
#define MT    8    // query points per gather pass
#define BM    32   // output rows per block (NPASS gather passes)
#define NPASS (BM / MT)
#define LDA   648  // sA row stride in halves: 640 + 8 pad -> row step = 324 dwords = 4 banks mod 32

typedef unsigned short u16x8  __attribute__((ext_vector_type(8)));
typedef float          f32x4  __attribute__((ext_vector_type(4)));
typedef _Float16       f16x8  __attribute__((ext_vector_type(8)));
typedef _Float16       f16x2  __attribute__((ext_vector_type(2)));

#define CVT_BLOCKS 2049   // ceil((N_S+1)*CIN/8 / 256)
#define PACK_BLOCKS 40    // ceil(8*20*64 / 256)

static __device__ __forceinline__ unsigned short f2h(float f) {
  return __builtin_bit_cast(unsigned short, (_Float16)f);
}

// v_cvt_pkrtz_f16_f32 packed to raw u32
static __device__ __forceinline__ unsigned int pkrtz_u32(float a, float b) {
  return __builtin_bit_cast(unsigned int, __builtin_amdgcn_cvt_pkrtz(a, b));
}

// half2-dot with fp32 accumulate: v_dot2_f32_f16
static __device__ __forceinline__ float fdot2u(unsigned int a, unsigned int b, float c) {
#if __has_builtin(__builtin_amdgcn_fdot2)
  return __builtin_amdgcn_fdot2(__builtin_bit_cast(f16x2, a),
                                __builtin_bit_cast(f16x2, b), c, false);
#else
  f16x2 ha = __builtin_bit_cast(f16x2, a), hb = __builtin_bit_cast(f16x2, b);
  return c + (float)ha[0] * (float)hb[0] + (float)ha[1] * (float)hb[1];
#endif
}

// ---- prep: x fp32 -> fp16 (+ zero shadow row) AND weight pack (fp16) --------
// Bpack[((ct*20 + ks)*64 + lane)*8 + j] = B[ks*32 + (lane>>4)*8 + j][ct*16 + (lane&15)]
__global__ void prep_kernel(const float* __restrict__ x,
                            const float* __restrict__ w,
                            unsigned short* __restrict__ xh,
                            unsigned short* __restrict__ bp) {
  if (blockIdx.x < CVT_BLOCKS) {
    long t = (long)blockIdx.x * blockDim.x + threadIdx.x;
    long off = t * 8;
    if (off >= (long)(N_S + 1) * CIN) return;
    u16x8 o;
    if (off < (long)N_S * CIN) {
      f32x4 a = *(const f32x4*)(x + off);
      f32x4 b = *(const f32x4*)(x + off + 4);
      o[0] = f2h(a[0]); o[1] = f2h(a[1]); o[2] = f2h(a[2]); o[3] = f2h(a[3]);
      o[4] = f2h(b[0]); o[5] = f2h(b[1]); o[6] = f2h(b[2]); o[7] = f2h(b[3]);
    } else {
      o = (u16x8)0;                       // shadow feature row = zeros
    }
    *(u16x8*)(xh + off) = o;
  } else {
    int t = (blockIdx.x - CVT_BLOCKS) * blockDim.x + threadIdx.x;
    if (t >= 8 * 20 * 64) return;
    int lane = t & 63;
    int frag = t >> 6;            // ct*20 + ks
    int ks = frag % 20;
    int ct = frag / 20;
    int row0 = ks * 32 + (lane >> 4) * 8;
    int col  = ct * 16 + (lane & 15);
    u16x8 o;
    #pragma unroll
    for (int j = 0; j < 8; ++j) o[j] = f2h(w[(row0 + j) * COUT + col]);
    *(u16x8*)(bp + (long)t * 8) = o;
  }
}

// ---- fused kernel: gather phases (A,A2,B,C into LDS A-tile) + MFMA GEMM -----
// LDS: 832 + 2560 + 960 + 4992 + 41472 = 50,816 B -> 3 blocks/CU (12 waves/CU).
// Eliminates the 83.9 MB wg HBM round trip entirely.
__global__ void __launch_bounds__(256, 3)
kpconv_fused(const float* __restrict__ q_pts, const float* __restrict__ s_pts,
             const float* __restrict__ gen_W, const float* __restrict__ gen_b,
             const int* __restrict__ inds, const unsigned short* __restrict__ xh,
             const unsigned short* __restrict__ bp, float* __restrict__ out) {

  __shared__ int            sh_ind[MT][NB_H];        //  832 B
  __shared__ float          sh_nbr[MT][80];          // 2560 B (78 used + 2 pad=-1)
  __shared__ float          sh_kp[MT][KP * 3];       //  960 B
  __shared__ unsigned int   sh_aw[MT][13][12];       // 4992 B
  __shared__ unsigned short sA[BM][LDA];             // 41472 B weighted A-tile (fp16)

  const int  tid  = threadIdx.x;
  const long row0 = (long)blockIdx.x * BM;

  #pragma unroll 1
  for (int pass = 0; pass < NPASS; ++pass) {
    const int pbase = (int)row0 + pass * MT;

    // ---- Phase A: neighbors = s_pad[ind] - q; pad channels 78,79 = -1 ----
    if (tid < MT * NB_H) {
      int m = tid / NB_H, h = tid % NB_H;
      int n = pbase + m;
      int ind = inds[n * NB_H + h];
      sh_ind[m][h] = ind;
      float sx, sy, sz;
      if ((unsigned)ind < (unsigned)N_S) {
        sx = s_pts[ind * 3 + 0]; sy = s_pts[ind * 3 + 1]; sz = s_pts[ind * 3 + 2];
      } else {
        sx = 1e6f; sy = 1e6f; sz = 1e6f;   // shadow support point
      }
      sh_nbr[m][h * 3 + 0] = sx - q_pts[n * 3 + 0];
      sh_nbr[m][h * 3 + 1] = sy - q_pts[n * 3 + 1];
      sh_nbr[m][h * 3 + 2] = sz - q_pts[n * 3 + 2];
    }
    if (tid < MT * 2) sh_nbr[tid >> 1][78 + (tid & 1)] = -1.0f;
    __syncthreads();

    // ---- Phase A2: kp = padded @ gen_W^T + gen_b ----
    if (tid < MT * KP * 3) {
      int m = tid / 30, r = tid % 30;
      const float* Wr = gen_W + r * (PAD_H * 3);
      const f32x4* W4 = (const f32x4*)Wr;
      const f32x4* N4 = (const f32x4*)&sh_nbr[m][0];
      f32x4 accv = {0.f, 0.f, 0.f, 0.f};
      #pragma unroll
      for (int j = 0; j < 20; ++j) accv += W4[j] * N4[j];
      sh_kp[m][r] = gen_b[r] - (Wr[80] + Wr[81] + Wr[82] + Wr[83])
                  + accv[0] + accv[1] + accv[2] + accv[3];
    }
    __syncthreads();

    // ---- Phase B: w-pairs (h0,h1) per (m,hp,k), packed half2 ----
    for (int p = tid; p < MT * 13 * KP; p += 256) {
      int k = p % KP;
      int t = p / KP;
      int m = t & (MT - 1);
      int hp = t >> 3;
      float kx = sh_kp[m][k * 3 + 0], ky = sh_kp[m][k * 3 + 1], kz = sh_kp[m][k * 3 + 2];
      int h0 = hp * 2;
      float dx0 = sh_nbr[m][h0 * 3 + 0] - kx;
      float dy0 = sh_nbr[m][h0 * 3 + 1] - ky;
      float dz0 = sh_nbr[m][h0 * 3 + 2] - kz;
      float w0 = fmaxf(1.0f - sqrtf(dx0 * dx0 + dy0 * dy0 + dz0 * dz0) * (1.0f / 1.2f), 0.0f);
      float dx1 = sh_nbr[m][h0 * 3 + 3] - kx;
      float dy1 = sh_nbr[m][h0 * 3 + 4] - ky;
      float dz1 = sh_nbr[m][h0 * 3 + 5] - kz;
      float w1 = fmaxf(1.0f - sqrtf(dx1 * dx1 + dy1 * dy1 + dz1 * dz1) * (1.0f / 1.2f), 0.0f);
      sh_aw[m][hp][k] = pkrtz_u32(w0, w1);
    }
    __syncthreads();

    // ---- Phase C: weighted[m][k][i] -> sA[pass*MT+m][k*64+i] (fp16, in LDS) ----
    {
      const int m  = tid >> 5;
      const int i0 = (tid & 31) * 2;
      float acc0[KP], acc1[KP];
      #pragma unroll
      for (int k = 0; k < KP; ++k) { acc0[k] = 0.f; acc1[k] = 0.f; }

      unsigned int xr[4];
      #pragma unroll
      for (int h = 0; h < 4; ++h)
        xr[h] = *(const unsigned int*)(xh + (long)sh_ind[m][h] * CIN + i0);

      #pragma unroll
      for (int p = 0; p < 13; ++p) {
        unsigned int r0 = xr[(2 * p) & 3];
        unsigned int r1 = xr[(2 * p + 1) & 3];
        if (2 * p + 4 < NB_H)
          xr[(2 * p) & 3] = *(const unsigned int*)(xh + (long)sh_ind[m][2 * p + 4] * CIN + i0);
        if (2 * p + 5 < NB_H)
          xr[(2 * p + 1) & 3] = *(const unsigned int*)(xh + (long)sh_ind[m][2 * p + 5] * CIN + i0);
        unsigned int pair0 = __builtin_amdgcn_perm(r1, r0, 0x05040100u);
        unsigned int pair1 = __builtin_amdgcn_perm(r1, r0, 0x07060302u);
        const unsigned int* wrow = &sh_aw[m][p][0];
        #pragma unroll
        for (int k = 0; k < KP; ++k) {
          unsigned int w2 = wrow[k];
          acc0[k] = fdot2u(w2, pair0, acc0[k]);
          acc1[k] = fdot2u(w2, pair1, acc1[k]);
        }
      }
      unsigned short* rowp = &sA[pass * MT + m][0];
      #pragma unroll
      for (int k = 0; k < KP; ++k)
        *(unsigned int*)(rowp + k * CIN + i0) = pkrtz_u32(acc0[k], acc1[k]);
    }
    __syncthreads();   // protect sh_* for next pass / sA complete before GEMM
  }

  // ---- GEMM phase: out[32][128] = sA[32][640] @ B[640][128] (fp16 MFMA) ----
  // 4 waves x 2 col-tiles x 2 row-tiles; bp fragments prefetched depth-4 from L2.
  {
    const int wave = tid >> 6;
    const int lane = tid & 63;
    const int ct0  = wave * 2, ct1 = ct0 + 1;
    const int arow = lane & 15;
    const int aq   = lane >> 4;

    f32x4 acc[2][2];
    #pragma unroll
    for (int rt = 0; rt < 2; ++rt)
      #pragma unroll
      for (int c = 0; c < 2; ++c) acc[rt][c] = (f32x4){0.f, 0.f, 0.f, 0.f};

    u16x8 pb0[4], pb1[4];
    #pragma unroll
    for (int d = 0; d < 4; ++d) {
      pb0[d] = *(const u16x8*)(bp + (long)((ct0 * 20 + d) * 64 + lane) * 8);
      pb1[d] = *(const u16x8*)(bp + (long)((ct1 * 20 + d) * 64 + lane) * 8);
    }

    #pragma unroll
    for (int ks = 0; ks < 20; ++ks) {
      f16x8 b0 = __builtin_bit_cast(f16x8, pb0[ks & 3]);
      f16x8 b1 = __builtin_bit_cast(f16x8, pb1[ks & 3]);
      if (ks + 4 < 20) {
        pb0[ks & 3] = *(const u16x8*)(bp + (long)((ct0 * 20 + ks + 4) * 64 + lane) * 8);
        pb1[ks & 3] = *(const u16x8*)(bp + (long)((ct1 * 20 + ks + 4) * 64 + lane) * 8);
      }
      #pragma unroll
      for (int rt = 0; rt < 2; ++rt) {
        u16x8 au = *(const u16x8*)&sA[rt * 16 + arow][ks * 32 + aq * 8];
        f16x8 a = __builtin_bit_cast(f16x8, au);
        acc[rt][0] = __builtin_amdgcn_mfma_f32_16x16x32_f16(a, b0, acc[rt][0], 0, 0, 0);
        acc[rt][1] = __builtin_amdgcn_mfma_f32_16x16x32_f16(a, b1, acc[rt][1], 0, 0, 0);
      }
    }

    // C/D layout: col = lane&15, row = (lane>>4)*4 + reg  [measured m89/m91]
    const int col   = lane & 15;
    const int rbase = aq * 4;
    #pragma unroll
    for (int rt = 0; rt < 2; ++rt)
      #pragma unroll
      for (int r = 0; r < 4; ++r) {
        long row = row0 + rt * 16 + rbase + r;
        __builtin_nontemporal_store(acc[rt][0][r], &out[row * COUT + ct0 * 16 + col]);
        __builtin_nontemporal_store(acc[rt][1][r], &out[row * COUT + ct1 * 16 + col]);
      }
  }
}

extern "C" void kernel_launch(void* const* d_in, const int* in_sizes, int n_in,
                              void* d_out, int out_size, void* d_ws, size_t ws_size,
                              hipStream_t stream) {
  const float* q_pts = (const float*)d_in[0];
  const float* s_pts = (const float*)d_in[1];
  const float* x     = (const float*)d_in[2];
  const float* gen_W = (const float*)d_in[3];
  const float* gen_b = (const float*)d_in[4];
  const float* wts   = (const float*)d_in[5];
  const int*   inds  = (const int*)d_in[6];
  float* out = (float*)d_out;

  unsigned short* xh = (unsigned short*)d_ws;            // (N_S+1)*CIN fp16 = 8.39 MB
  unsigned short* bp = xh + (size_t)(N_S + 1) * CIN;     // 81920 fp16 = 160 KB

  prep_kernel<<<CVT_BLOCKS + PACK_BLOCKS, 256, 0, stream>>>(x, wts, xh, bp);
  kpconv_fused<<<N_Q / BM, 256, 0, stream>>>(q_pts, s_pts, gen_W, gen_b,
                                             inds, xh, bp, out);
}

// Round 2
// 174.117 us; speedup vs baseline: 1.0453x; 1.0453x over previous
//
#include <hip/hip_runtime.h>
#include <stdint.h>

#define N_Q   65536
#define N_S   65536
#define NB_H  26
#define PAD_H 28
#define KP    10
#define CIN   64
#define COUT  128
#define MT    8    // query points per gather pass
#define BM    16   // output rows per block (NPASS gather passes)
#define NPASS (BM / MT)

typedef unsigned short u16x8  __attribute__((ext_vector_type(8)));
typedef float          f32x4  __attribute__((ext_vector_type(4)));
typedef _Float16       f16x8  __attribute__((ext_vector_type(8)));
typedef _Float16       f16x2  __attribute__((ext_vector_type(2)));

#define CVT_BLOCKS 2049   // ceil((N_S+1)*CIN/8 / 256)
#define PACK_BLOCKS 40    // ceil(8*20*64 / 256)

static __device__ __forceinline__ unsigned short f2h(float f) {
  return __builtin_bit_cast(unsigned short, (_Float16)f);
}

// v_cvt_pkrtz_f16_f32 packed to raw u32
static __device__ __forceinline__ unsigned int pkrtz_u32(float a, float b) {
  return __builtin_bit_cast(unsigned int, __builtin_amdgcn_cvt_pkrtz(a, b));
}

// half2-dot with fp32 accumulate: v_dot2_f32_f16
static __device__ __forceinline__ float fdot2u(unsigned int a, unsigned int b, float c) {
#if __has_builtin(__builtin_amdgcn_fdot2)
  return __builtin_amdgcn_fdot2(__builtin_bit_cast(f16x2, a),
                                __builtin_bit_cast(f16x2, b), c, false);
#else
  f16x2 ha = __builtin_bit_cast(f16x2, a), hb = __builtin_bit_cast(f16x2, b);
  return c + (float)ha[0] * (float)hb[0] + (float)ha[1] * (float)hb[1];
#endif
}

// ---- prep: x fp32 -> fp16 (+ zero shadow row) AND weight pack (fp16) --------
// Bpack[((ct*20 + ks)*64 + lane)*8 + j] = B[ks*32 + (lane>>4)*8 + j][ct*16 + (lane&15)]
__global__ void prep_kernel(const float* __restrict__ x,
                            const float* __restrict__ w,
                            unsigned short* __restrict__ xh,
                            unsigned short* __restrict__ bp) {
  if (blockIdx.x < CVT_BLOCKS) {
    long t = (long)blockIdx.x * blockDim.x + threadIdx.x;
    long off = t * 8;
    if (off >= (long)(N_S + 1) * CIN) return;
    u16x8 o;
    if (off < (long)N_S * CIN) {
      f32x4 a = *(const f32x4*)(x + off);
      f32x4 b = *(const f32x4*)(x + off + 4);
      o[0] = f2h(a[0]); o[1] = f2h(a[1]); o[2] = f2h(a[2]); o[3] = f2h(a[3]);
      o[4] = f2h(b[0]); o[5] = f2h(b[1]); o[6] = f2h(b[2]); o[7] = f2h(b[3]);
    } else {
      o = (u16x8)0;                       // shadow feature row = zeros
    }
    *(u16x8*)(xh + off) = o;
  } else {
    int t = (blockIdx.x - CVT_BLOCKS) * blockDim.x + threadIdx.x;
    if (t >= 8 * 20 * 64) return;
    int lane = t & 63;
    int frag = t >> 6;            // ct*20 + ks
    int ks = frag % 20;
    int ct = frag / 20;
    int row0 = ks * 32 + (lane >> 4) * 8;
    int col  = ct * 16 + (lane & 15);
    u16x8 o;
    #pragma unroll
    for (int j = 0; j < 8; ++j) o[j] = f2h(w[(row0 + j) * COUT + col]);
    *(u16x8*)(bp + (long)t * 8) = o;
  }
}

// ---- fused kernel: gather phases (A,A2,B,C into LDS A-frags) + MFMA GEMM ----
// LDS: 832 + 2560 + 960 + 4992 + 20480 = 29,824 B -> 5 blocks/CU (20 waves/CU,
// 62.5% occ -- round-1 lesson: gather is latency-bound, occupancy IS the speed).
// sA stored fragment-major with transposed lane map p = row*4 + q:
//   - phase-C u32 stores: bank = (row*16 + q*4 + e2) & 31 -> 2 lanes/bank (free)
//   - GEMM ds_read_b128: linear 1 KB/frag at base + ks*1024 imm offsets (conflict-free)
__global__ void __launch_bounds__(256, 5)
kpconv_fused(const float* __restrict__ q_pts, const float* __restrict__ s_pts,
             const float* __restrict__ gen_W, const float* __restrict__ gen_b,
             const int* __restrict__ inds, const unsigned short* __restrict__ xh,
             const unsigned short* __restrict__ bp, float* __restrict__ out) {

  __shared__ int            sh_ind[MT][NB_H];        //  832 B
  __shared__ float          sh_nbr[MT][80];          // 2560 B (78 used + 2 pad=-1)
  __shared__ float          sh_kp[MT][KP * 3];       //  960 B
  __shared__ unsigned int   sh_aw[MT][13][12];       // 4992 B
  __shared__ unsigned short sA[20 * 512];            // 20480 B: frag ks=0..19, lane p, 8 halves

  const int  tid  = threadIdx.x;
  const long row0 = (long)blockIdx.x * BM;

  #pragma unroll 1
  for (int pass = 0; pass < NPASS; ++pass) {
    const int pbase = (int)row0 + pass * MT;

    // ---- Phase A: neighbors = s_pad[ind] - q; pad channels 78,79 = -1 ----
    if (tid < MT * NB_H) {
      int m = tid / NB_H, h = tid % NB_H;
      int n = pbase + m;
      int ind = inds[n * NB_H + h];
      sh_ind[m][h] = ind;
      float sx, sy, sz;
      if ((unsigned)ind < (unsigned)N_S) {
        sx = s_pts[ind * 3 + 0]; sy = s_pts[ind * 3 + 1]; sz = s_pts[ind * 3 + 2];
      } else {
        sx = 1e6f; sy = 1e6f; sz = 1e6f;   // shadow support point
      }
      sh_nbr[m][h * 3 + 0] = sx - q_pts[n * 3 + 0];
      sh_nbr[m][h * 3 + 1] = sy - q_pts[n * 3 + 1];
      sh_nbr[m][h * 3 + 2] = sz - q_pts[n * 3 + 2];
    }
    if (tid < MT * 2) sh_nbr[tid >> 1][78 + (tid & 1)] = -1.0f;
    __syncthreads();

    // ---- Phase A2: kp = padded @ gen_W^T + gen_b ----
    if (tid < MT * KP * 3) {
      int m = tid / 30, r = tid % 30;
      const float* Wr = gen_W + r * (PAD_H * 3);
      const f32x4* W4 = (const f32x4*)Wr;
      const f32x4* N4 = (const f32x4*)&sh_nbr[m][0];
      f32x4 accv = {0.f, 0.f, 0.f, 0.f};
      #pragma unroll
      for (int j = 0; j < 20; ++j) accv += W4[j] * N4[j];
      sh_kp[m][r] = gen_b[r] - (Wr[80] + Wr[81] + Wr[82] + Wr[83])
                  + accv[0] + accv[1] + accv[2] + accv[3];
    }
    __syncthreads();

    // ---- Phase B: w-pairs (h0,h1) per (m,hp,k), packed half2 ----
    for (int p = tid; p < MT * 13 * KP; p += 256) {
      int k = p % KP;
      int t = p / KP;
      int m = t & (MT - 1);
      int hp = t >> 3;
      float kx = sh_kp[m][k * 3 + 0], ky = sh_kp[m][k * 3 + 1], kz = sh_kp[m][k * 3 + 2];
      int h0 = hp * 2;
      float dx0 = sh_nbr[m][h0 * 3 + 0] - kx;
      float dy0 = sh_nbr[m][h0 * 3 + 1] - ky;
      float dz0 = sh_nbr[m][h0 * 3 + 2] - kz;
      float w0 = fmaxf(1.0f - sqrtf(dx0 * dx0 + dy0 * dy0 + dz0 * dz0) * (1.0f / 1.2f), 0.0f);
      float dx1 = sh_nbr[m][h0 * 3 + 3] - kx;
      float dy1 = sh_nbr[m][h0 * 3 + 4] - ky;
      float dz1 = sh_nbr[m][h0 * 3 + 5] - kz;
      float w1 = fmaxf(1.0f - sqrtf(dx1 * dx1 + dy1 * dy1 + dz1 * dz1) * (1.0f / 1.2f), 0.0f);
      sh_aw[m][hp][k] = pkrtz_u32(w0, w1);
    }
    __syncthreads();

    // ---- Phase C: weighted[m][k][i0,i0+1] -> sA frag-major (fp16, in LDS) ----
    // depth-8 rotating register prefetch (3 iterations of latency cover).
    {
      const int m  = tid >> 5;
      const int i0 = (tid & 31) * 2;
      float acc0[KP], acc1[KP];
      #pragma unroll
      for (int k = 0; k < KP; ++k) { acc0[k] = 0.f; acc1[k] = 0.f; }

      unsigned int xr[8];
      #pragma unroll
      for (int h = 0; h < 8; ++h)
        xr[h] = *(const unsigned int*)(xh + (long)sh_ind[m][h] * CIN + i0);

      #pragma unroll
      for (int p = 0; p < 13; ++p) {
        unsigned int r0 = xr[(2 * p) & 7];
        unsigned int r1 = xr[(2 * p + 1) & 7];
        if (2 * p + 8 < NB_H)
          xr[(2 * p) & 7] = *(const unsigned int*)(xh + (long)sh_ind[m][2 * p + 8] * CIN + i0);
        if (2 * p + 9 < NB_H)
          xr[(2 * p + 1) & 7] = *(const unsigned int*)(xh + (long)sh_ind[m][2 * p + 9] * CIN + i0);
        unsigned int pair0 = __builtin_amdgcn_perm(r1, r0, 0x05040100u);
        unsigned int pair1 = __builtin_amdgcn_perm(r1, r0, 0x07060302u);
        const unsigned int* wrow = &sh_aw[m][p][0];
        #pragma unroll
        for (int k = 0; k < KP; ++k) {
          unsigned int w2 = wrow[k];
          acc0[k] = fdot2u(w2, pair0, acc0[k]);
          acc1[k] = fdot2u(w2, pair1, acc1[k]);
        }
      }
      // fragment-major store: kdim = k*64 + i0; ks = kdim>>5; e = kdim&31;
      // lane slot p = row*4 + (e>>3); halves offset = ks*512 + p*8 + (e&7)
      const int row  = pass * MT + m;          // 0..15
      const int qhi  = i0 >> 5;                // 0/1 -> ks parity
      const int e    = i0 & 31;
      const int slot = row * 4 + (e >> 3);
      const int hoff = slot * 8 + (e & 7);
      #pragma unroll
      for (int k = 0; k < KP; ++k)
        *(unsigned int*)(sA + (k * 2 + qhi) * 512 + hoff) = pkrtz_u32(acc0[k], acc1[k]);
    }
    __syncthreads();   // protect sh_* for next pass / sA complete before GEMM
  }

  // ---- GEMM phase: out[16][128] = A[16][640] @ B[640][128] (fp16 MFMA) ----
  // 4 waves x 2 col-tiles; bp fragments prefetched depth-4 from L2;
  // A-frags read linearly from sA (lane l -> slot (l&15)*4 + (l>>4)).
  {
    const int wave = tid >> 6;
    const int lane = tid & 63;
    const int ct0  = wave * 2, ct1 = ct0 + 1;
    const int aoff = ((lane & 15) * 4 + (lane >> 4)) * 8;   // halves within frag

    f32x4 acc[2];
    acc[0] = (f32x4){0.f, 0.f, 0.f, 0.f};
    acc[1] = (f32x4){0.f, 0.f, 0.f, 0.f};

    u16x8 pb0[4], pb1[4];
    #pragma unroll
    for (int d = 0; d < 4; ++d) {
      pb0[d] = *(const u16x8*)(bp + (long)((ct0 * 20 + d) * 64 + lane) * 8);
      pb1[d] = *(const u16x8*)(bp + (long)((ct1 * 20 + d) * 64 + lane) * 8);
    }

    #pragma unroll
    for (int ks = 0; ks < 20; ++ks) {
      f16x8 b0 = __builtin_bit_cast(f16x8, pb0[ks & 3]);
      f16x8 b1 = __builtin_bit_cast(f16x8, pb1[ks & 3]);
      if (ks + 4 < 20) {
        pb0[ks & 3] = *(const u16x8*)(bp + (long)((ct0 * 20 + ks + 4) * 64 + lane) * 8);
        pb1[ks & 3] = *(const u16x8*)(bp + (long)((ct1 * 20 + ks + 4) * 64 + lane) * 8);
      }
      u16x8 au = *(const u16x8*)&sA[ks * 512 + aoff];
      f16x8 a = __builtin_bit_cast(f16x8, au);
      acc[0] = __builtin_amdgcn_mfma_f32_16x16x32_f16(a, b0, acc[0], 0, 0, 0);
      acc[1] = __builtin_amdgcn_mfma_f32_16x16x32_f16(a, b1, acc[1], 0, 0, 0);
    }

    // C/D layout: col = lane&15, row = (lane>>4)*4 + reg  [measured m89/m91]
    const int col   = lane & 15;
    const int rbase = (lane >> 4) * 4;
    #pragma unroll
    for (int r = 0; r < 4; ++r) {
      long row = row0 + rbase + r;
      __builtin_nontemporal_store(acc[0][r], &out[row * COUT + ct0 * 16 + col]);
      __builtin_nontemporal_store(acc[1][r], &out[row * COUT + ct1 * 16 + col]);
    }
  }
}

extern "C" void kernel_launch(void* const* d_in, const int* in_sizes, int n_in,
                              void* d_out, int out_size, void* d_ws, size_t ws_size,
                              hipStream_t stream) {
  const float* q_pts = (const float*)d_in[0];
  const float* s_pts = (const float*)d_in[1];
  const float* x     = (const float*)d_in[2];
  const float* gen_W = (const float*)d_in[3];
  const float* gen_b = (const float*)d_in[4];
  const float* wts   = (const float*)d_in[5];
  const int*   inds  = (const int*)d_in[6];
  float* out = (float*)d_out;

  unsigned short* xh = (unsigned short*)d_ws;            // (N_S+1)*CIN fp16 = 8.39 MB
  unsigned short* bp = xh + (size_t)(N_S + 1) * CIN;     // 81920 fp16 = 160 KB

  prep_kernel<<<CVT_BLOCKS + PACK_BLOCKS, 256, 0, stream>>>(x, wts, xh, bp);
  kpconv_fused<<<N_Q / BM, 256, 0, stream>>>(q_pts, s_pts, gen_W, gen_b,
                                             inds, xh, bp, out);
}